// Round 1
// baseline (501.212 us; speedup 1.0000x reference)
//
#include <hip/hip_runtime.h>
#include <hip/hip_bf16.h>

// Soft cross entropy: loss_i = logZ_i * sum(t_i) - sum(t_i * x_i),
// logZ_i = max_i + log(sum(exp(x - max))). Output = mean over rows.
// n = 131072 rows, K = 512 cols, fp32. Memory-bound: 536.9 MB read, floor ~85us.

#define K_COLS 512

__global__ __launch_bounds__(256, 2)
void sce_kernel(const float* __restrict__ inp, const float* __restrict__ tgt,
                float* __restrict__ out, int n, float inv_n) {
    const int lane = threadIdx.x & 63;
    const int wave = threadIdx.x >> 6;                 // 0..3
    const int waves_per_block = blockDim.x >> 6;       // 4
    const int gwave = blockIdx.x * waves_per_block + wave;
    const int total_waves = gridDim.x * waves_per_block;

    float acc = 0.0f;

    for (int row = gwave; row < n; row += total_waves) {
        const float4* ip = (const float4*)(inp + (size_t)row * K_COLS);
        const float4* tp = (const float4*)(tgt + (size_t)row * K_COLS);
        // lane l covers cols [4l,4l+4) and [256+4l, 256+4l+4): coalesced 1KiB/inst
        float4 x0 = ip[lane];
        float4 x1 = ip[lane + 64];
        float4 t0 = tp[lane];
        float4 t1 = tp[lane + 64];

        // per-lane max over its 8 elements
        float m = fmaxf(fmaxf(fmaxf(x0.x, x0.y), fmaxf(x0.z, x0.w)),
                        fmaxf(fmaxf(x1.x, x1.y), fmaxf(x1.z, x1.w)));
        // wave-wide max (butterfly, 6 steps, wave=64)
        #pragma unroll
        for (int off = 32; off > 0; off >>= 1)
            m = fmaxf(m, __shfl_xor(m, off, 64));

        // per-lane partial sums (inputs still in registers — single pass)
        float es = __expf(x0.x - m) + __expf(x0.y - m) +
                   __expf(x0.z - m) + __expf(x0.w - m) +
                   __expf(x1.x - m) + __expf(x1.y - m) +
                   __expf(x1.z - m) + __expf(x1.w - m);
        float ts = (t0.x + t0.y) + (t0.z + t0.w) +
                   (t1.x + t1.y) + (t1.z + t1.w);
        float tx = 0.0f;
        tx = fmaf(t0.x, x0.x, tx); tx = fmaf(t0.y, x0.y, tx);
        tx = fmaf(t0.z, x0.z, tx); tx = fmaf(t0.w, x0.w, tx);
        tx = fmaf(t1.x, x1.x, tx); tx = fmaf(t1.y, x1.y, tx);
        tx = fmaf(t1.z, x1.z, tx); tx = fmaf(t1.w, x1.w, tx);

        // wave-wide sums (3 values per butterfly step)
        #pragma unroll
        for (int off = 32; off > 0; off >>= 1) {
            es += __shfl_xor(es, off, 64);
            ts += __shfl_xor(ts, off, 64);
            tx += __shfl_xor(tx, off, 64);
        }

        float logZ = m + __logf(es);
        acc = fmaf(logZ, ts, acc - tx);   // acc += logZ*ts - tx (same on all lanes)
    }

    // block reduce: one value per wave -> one atomic per block
    __shared__ float smem[8];
    if (lane == 0) smem[wave] = acc;
    __syncthreads();
    if (threadIdx.x == 0) {
        float b = 0.0f;
        for (int w = 0; w < waves_per_block; ++w) b += smem[w];
        atomicAdd(out, b * inv_n);   // pre-scaled: accumulated magnitude ~1.7e3
    }
}

extern "C" void kernel_launch(void* const* d_in, const int* in_sizes, int n_in,
                              void* d_out, int out_size, void* d_ws, size_t ws_size,
                              hipStream_t stream) {
    const float* inp = (const float*)d_in[0];
    const float* tgt = (const float*)d_in[1];
    float* out = (float*)d_out;
    const int n = in_sizes[0] / K_COLS;   // 131072 rows

    // d_out is re-poisoned to 0xAA before every timed launch
    hipMemsetAsync(out, 0, sizeof(float), stream);

    const int blocks = 4096;   // 16384 waves, 8 rows/wave grid-stride
    sce_kernel<<<blocks, 256, 0, stream>>>(inp, tgt, out, n, 1.0f / (float)n);
}